// Round 17
// baseline (91.188 us; speedup 1.0000x reference)
//
#include <hip/hip_runtime.h>
#include <hip/hip_fp16.h>

typedef _Float16 f16;
typedef _Float16 half4 __attribute__((ext_vector_type(4)));
typedef _Float16 half8 __attribute__((ext_vector_type(8)));
typedef float f32x4 __attribute__((ext_vector_type(4)));

#define BATCH 8
#define NTOK 2048
#define FIN 256
#define FOUT 256
#define ALPHA 0.2f

// WhT swizzled layout: [b][slab(32)][o(256)][u(8)][q(8)] f16; logical
// Wh[n][o] (n = slab*64 + jg8*8 + jq) lives at u = jg8 ^ (o & 7).
// Each slab is a contiguous 32 KB block == its LDS image in k_attn.

__device__ __forceinline__ void gload16(const void* g, void* l) {
    __builtin_amdgcn_global_load_lds(
        (const __attribute__((address_space(1))) unsigned int*)(g),
        (__attribute__((address_space(3))) unsigned int*)(l), 16, 0, 0);
}

// ---------------- K0: W[k][o] fp32 -> WT[o][k] fp16 ----------------
__global__ void k_wt(const float* __restrict__ W, f16* __restrict__ WT) {
    __shared__ float t[32][33];
    int o0 = blockIdx.x * 32, k0 = blockIdx.y * 32;
    int tx = threadIdx.x, ty = threadIdx.y;
    t[ty][tx] = W[(k0 + ty) * FOUT + o0 + tx];
    __syncthreads();
    WT[(o0 + ty) * FIN + (k0 + tx)] = (f16)t[tx][ty];
}

// ---------------- K pack: adj -> bitmask. STANDALONE, 0 LDS, 1024 blocks ----------------
// 4/CU resident (16 waves/CU), 16 hoisted loads (64 B/lane in flight) + 16 ballots.
__global__ __launch_bounds__(256) void k_pack(const int* __restrict__ adj,
                                              unsigned long long* __restrict__ mask) {
    int t = threadIdx.x;
    int lane = t & 63, w = t >> 6;
    int wid = blockIdx.x * 4 + w;                  // 0..4095
    const int* base0 = adj + (size_t)wid * 8192;   // 32 KB contiguous / wave
    unsigned long long* mdst = mask + (size_t)wid * 128;
    for (int it = 0; it < 8; it++) {
        const int* base = base0 + it * 1024;
        int v[16];
#pragma unroll
        for (int k = 0; k < 16; k++) v[k] = base[k * 64 + lane];
        unsigned long long mv[16];
#pragma unroll
        for (int k = 0; k < 16; k++) mv[k] = __ballot(v[k] > 0);
        if (lane < 16) {
            unsigned long long r = mv[0];
#pragma unroll
            for (int k = 1; k < 16; k++) r = (lane == k) ? mv[k] : r;
            mdst[it * 16 + lane] = r;
        }
    }
}

// ---------------- K1: gemm -> swizzled WhT slab + fused s1/s2 epilogue ----------------
__global__ __launch_bounds__(256) void k_gemm(const float* __restrict__ x,
                                              const f16* __restrict__ WT,
                                              const float* __restrict__ a,
                                              f16* __restrict__ WhT,
                                              float* __restrict__ s1,
                                              float* __restrict__ s2) {
    __shared__ __align__(16) char gsmem[46080];
    int t = threadIdx.x;
    int lane = t & 63, w = t >> 6;
    f16* Ah = (f16*)gsmem;               // [64][72]
    f16* Bt = (f16*)(gsmem + 9216);      // [256][72]
    int m0 = blockIdx.x * 64;
    int lr = lane & 15, lg = lane >> 4;
    f32x4 acc[4][4] = {};

    for (int k0 = 0; k0 < FIN; k0 += 64) {
        {
            int r = t >> 2, c = (t & 3) * 16;
            const float* src = x + (size_t)(m0 + r) * FIN + k0 + c;
            f32x4 v0 = *(const f32x4*)(src);
            f32x4 v1 = *(const f32x4*)(src + 4);
            f32x4 v2 = *(const f32x4*)(src + 8);
            f32x4 v3 = *(const f32x4*)(src + 12);
            half8 h0, h1;
#pragma unroll
            for (int q = 0; q < 4; q++) {
                h0[q] = (f16)v0[q]; h0[q + 4] = (f16)v1[q];
                h1[q] = (f16)v2[q]; h1[q + 4] = (f16)v3[q];
            }
            f16* dst = Ah + r * 72 + c;
            *(half8*)dst = h0;
            *(half8*)(dst + 8) = h1;
        }
        {
            const f16* src = WT + (size_t)t * FIN + k0;
            f16* dst = Bt + t * 72;
#pragma unroll
            for (int q = 0; q < 8; q++)
                *(half8*)(dst + q * 8) = *(const half8*)(src + q * 8);
        }
        __syncthreads();
#pragma unroll
        for (int kc = 0; kc < 2; kc++) {
            int krow = kc * 32 + lg * 8;
            half8 af[4], bf[4];
#pragma unroll
            for (int fi = 0; fi < 4; fi++)
                af[fi] = *(half8*)(Ah + (fi * 16 + lr) * 72 + krow);
#pragma unroll
            for (int fo = 0; fo < 4; fo++)
                bf[fo] = *(half8*)(Bt + (w * 64 + fo * 16 + lr) * 72 + krow);
#pragma unroll
            for (int fi = 0; fi < 4; fi++)
#pragma unroll
                for (int fo = 0; fo < 4; fo++)
                    acc[fi][fo] = __builtin_amdgcn_mfma_f32_16x16x32_f16(
                        af[fi], bf[fo], acc[fi][fo], 0, 0, 0);
        }
        __syncthreads();
    }

    int b = m0 >> 11;
    int slab_i = (m0 & (NTOK - 1)) >> 6;
    int nbase = m0 & (NTOK - 1);

    float* sred = (float*)gsmem;          // aliases Ah
    f16* slab = (f16*)(gsmem + 9216);     // 32 KB slab image (aliases Bt)
    float a1v[4], a2v[4];
#pragma unroll
    for (int fo = 0; fo < 4; fo++) {
        int o = w * 64 + fo * 16 + lr;
        a1v[fo] = a[o];
        a2v[fo] = a[FOUT + o];
    }
#pragma unroll
    for (int fi = 0; fi < 4; fi++) {
        f32x4 p1 = {}, p2 = {};
#pragma unroll
        for (int fo = 0; fo < 4; fo++) {
            p1 += acc[fi][fo] * a1v[fo];
            p2 += acc[fi][fo] * a2v[fo];
        }
#pragma unroll
        for (int q = 0; q < 4; q++) {
#pragma unroll
            for (int d = 1; d < 16; d <<= 1) {
                p1[q] += __shfl_xor(p1[q], d);
                p2[q] += __shfl_xor(p2[q], d);
            }
        }
        if (lr == 0) {
            int row = fi * 16 + lg * 4;
#pragma unroll
            for (int q = 0; q < 4; q++) {
                sred[w * 64 + row + q] = p1[q];
                sred[256 + w * 64 + row + q] = p2[q];
            }
        }
    }
#pragma unroll
    for (int fi = 0; fi < 4; fi++) {
        int jg8 = fi * 2 + (lg >> 1), jq0 = (lg & 1) * 4;
#pragma unroll
        for (int fo = 0; fo < 4; fo++) {
            int o = w * 64 + fo * 16 + lr;
            half4 hv;
#pragma unroll
            for (int q = 0; q < 4; q++) hv[q] = (f16)acc[fi][fo][q];
            *(half4*)(slab + o * 64 + ((jg8 ^ (o & 7)) * 8) + jq0) = hv;
        }
    }
    __syncthreads();

    if (t < 64) {
        s1[(size_t)b * NTOK + nbase + t] =
            sred[t] + sred[64 + t] + sred[128 + t] + sred[192 + t];
    } else if (t < 128) {
        int r2 = t - 64;
        s2[(size_t)b * NTOK + nbase + r2] =
            sred[256 + r2] + sred[320 + r2] + sred[384 + r2] + sred[448 + r2];
    }
    {
        const int4* sl = (const int4*)slab;
        int4* gd = (int4*)(WhT + ((size_t)(b * 32 + slab_i) * 256) * 64);
#pragma unroll
        for (int i = 0; i < 8; i++) gd[i * 256 + t] = sl[i * 256 + t];
    }
}

// ---------------- K3: fused rowmax + softmax(fixed shift) + P@Wh + ELU ----------------
// R12/R14/R15/R16-validated structure; k_rowmax folded in: s2max computed
// in-block from the already-staged s2_lds (fp max is order-independent ->
// arithmetic identical to the old k_rowmax path).
__global__ __launch_bounds__(512, 2) void k_attn(const unsigned* __restrict__ mask32,
                                                 const f16* __restrict__ WhT,
                                                 const float* __restrict__ s1g,
                                                 const float* __restrict__ s2g,
                                                 float* __restrict__ out) {
    __shared__ __align__(16) char smem[65536 + 8192 + 512 + 64];
    f16* Bl = (f16*)smem;                          // [2][16384] f16 (2x32KB)
    float* s2_lds = (float*)(smem + 65536);        // [2048]
    float* lpart = (float*)(smem + 65536 + 8192);  // [2][64]
    float* wmax = (float*)(smem + 65536 + 8192 + 512);  // [8]

    int b = blockIdx.x & 7;                        // batch -> XCD pinning
    int i0 = (blockIdx.x >> 3) * 64;
    int t = threadIdx.x;
    int lane = t & 63, w = t >> 6;
    int js = w & 1, oh = (w >> 1) & 1, rg = w >> 2;
    int lr = lane & 15, lg = lane >> 4;

    {
        f32x4 sv4 = ((const f32x4*)(s2g + (size_t)b * NTOK))[t];
        ((f32x4*)s2_lds)[t] = sv4;
        float tmx = fmaxf(fmaxf(sv4[0], sv4[1]), fmaxf(sv4[2], sv4[3]));
#pragma unroll
        for (int d = 1; d < 64; d <<= 1) tmx = fmaxf(tmx, __shfl_xor(tmx, d));
        if (lane == 0) wmax[w] = tmx;
    }

    const char* wsrc = (const char*)WhT + (size_t)b * (32 * 32768);
    {
        const char* src = wsrc + (w * 4) * 1024 + lane * 16;
        char* dst = (char*)Bl + (w * 4) * 1024;
#pragma unroll
        for (int k = 0; k < 4; k++) gload16(src + k * 1024, dst + k * 1024);
    }

    int r0 = i0 + rg * 32 + lr, r1 = r0 + 16;
    float s1r0 = s1g[(size_t)b * NTOK + r0];
    float s1r1 = s1g[(size_t)b * NTOK + r1];
    const unsigned* mr0 = mask32 + (size_t)(b * NTOK + r0) * 64 + js;
    const unsigned* mr1 = mask32 + (size_t)(b * NTOK + r1) * 64 + js;

    f32x4 acc0[8] = {}, acc1[8] = {};
    float l0 = 0.f, l1 = 0.f;
    int rswz = ((js * 4 + lg) ^ (lr & 7)) * 8;

    unsigned bw0 = mr0[0], bw1 = mr1[0];

    __syncthreads();                                // s2 + wmax + slab0 staged

    float s2m = wmax[0];
#pragma unroll
    for (int k = 1; k < 8; k++) s2m = fmaxf(s2m, wmax[k]);
    float tx0 = s1r0 + s2m;
    float mx0 = fmaxf(tx0, ALPHA * tx0);
    float tx1 = s1r1 + s2m;
    float mx1 = fmaxf(tx1, ALPHA * tx1);

    for (int s = 0; s < 32; s++) {
        int buf = s & 1;
        if (s < 31) {
            const char* src = wsrc + (size_t)(s + 1) * 32768 + (w * 4) * 1024 + lane * 16;
            char* dst = (char*)Bl + (buf ^ 1) * 32768 + (w * 4) * 1024;
#pragma unroll
            for (int k = 0; k < 4; k++) gload16(src + k * 1024, dst + k * 1024);
        }

        unsigned cw0 = bw0, cw1 = bw1;
        if (s < 31) { bw0 = mr0[(s + 1) * 2]; bw1 = mr1[(s + 1) * 2]; }
        unsigned bits0 = (cw0 >> (lg * 8)) & 0xffu;
        unsigned bits1 = (cw1 >> (lg * 8)) & 0xffu;

        int sb = s * 64 + js * 32 + lg * 8;
        f32x4 sA = *(const f32x4*)&s2_lds[sb];
        f32x4 sB = *(const f32x4*)&s2_lds[sb + 4];

        half8 ph0, ph1;
#pragma unroll
        for (int q = 0; q < 8; q++) {
            float sv = q < 4 ? sA[q & 3] : sB[q & 3];
            float sx = s1r0 + sv;
            float ev = fmaxf(sx, ALPHA * sx);
            float p = ((bits0 >> q) & 1) ? __expf(ev - mx0) : 0.f;
            l0 += p; ph0[q] = (f16)p;
            float sy = s1r1 + sv;
            float eu = fmaxf(sy, ALPHA * sy);
            float u = ((bits1 >> q) & 1) ? __expf(eu - mx1) : 0.f;
            l1 += u; ph1[q] = (f16)u;
        }

        const f16* bbase = Bl + buf * 16384 + (oh * 128 + lr) * 64 + rswz;
#pragma unroll
        for (int ot = 0; ot < 8; ot++) {
            half8 bf = *(const half8*)(bbase + ot * (16 * 64));
            acc0[ot] = __builtin_amdgcn_mfma_f32_16x16x32_f16(ph0, bf, acc0[ot], 0, 0, 0);
            acc1[ot] = __builtin_amdgcn_mfma_f32_16x16x32_f16(ph1, bf, acc1[ot], 0, 0, 0);
        }
        __syncthreads();
    }

    l0 += __shfl_xor(l0, 16); l0 += __shfl_xor(l0, 32);
    l1 += __shfl_xor(l1, 16); l1 += __shfl_xor(l1, 32);
    if (oh == 0 && lg == 0) {
        lpart[js * 64 + rg * 32 + lr] = l0;
        lpart[js * 64 + rg * 32 + 16 + lr] = l1;
    }
    __syncthreads();

    float* accx = (float*)smem;                     // [64][260]
    if (js == 1) {
#pragma unroll
        for (int ot = 0; ot < 8; ot++)
#pragma unroll
            for (int q = 0; q < 4; q++) {
                accx[(rg * 32 + lg * 4 + q) * 260 + oh * 128 + ot * 16 + lr] = acc0[ot][q];
                accx[(rg * 32 + 16 + lg * 4 + q) * 260 + oh * 128 + ot * 16 + lr] = acc1[ot][q];
            }
    }
    __syncthreads();
    if (js == 0) {
        f32x4 rl0, rl1;
#pragma unroll
        for (int q = 0; q < 4; q++) {
            int ra = rg * 32 + lg * 4 + q, rb = ra + 16;
            rl0[q] = 1.f / (lpart[ra] + lpart[64 + ra]);
            rl1[q] = 1.f / (lpart[rb] + lpart[64 + rb]);
        }
#pragma unroll
        for (int ot = 0; ot < 8; ot++) {
            int o = oh * 128 + ot * 16 + lr;
#pragma unroll
            for (int q = 0; q < 4; q++) {
                int ra = rg * 32 + lg * 4 + q;
                float u = (acc0[ot][q] + accx[ra * 260 + o]) * rl0[q];
                u = u > 0.f ? u : __expf(u) - 1.f;
                __builtin_nontemporal_store(u, &out[((size_t)(b * NTOK + i0 + ra)) * FOUT + o]);
                int rb = ra + 16;
                float v = (acc1[ot][q] + accx[rb * 260 + o]) * rl1[q];
                v = v > 0.f ? v : __expf(v) - 1.f;
                __builtin_nontemporal_store(v, &out[((size_t)(b * NTOK + i0 + rb)) * FOUT + o]);
            }
        }
    }
}

extern "C" void kernel_launch(void* const* d_in, const int* in_sizes, int n_in,
                              void* d_out, int out_size, void* d_ws, size_t ws_size,
                              hipStream_t stream) {
    const float* x = (const float*)d_in[0];
    const int* adj = (const int*)d_in[1];
    const float* W = (const float*)d_in[2];
    const float* a = (const float*)d_in[3];
    float* out = (float*)d_out;

    char* ws = (char*)d_ws;
    f16* WT = (f16*)ws;                                     // 128 KB
    f16* WhT = (f16*)(ws + 131072);                         // 8 MB swizzled
    float* s1 = (float*)(ws + 131072 + 8388608);            // 64 KB
    float* s2 = s1 + BATCH * NTOK;                          // 64 KB
    unsigned long long* mask64 =
        (unsigned long long*)(ws + 131072 + 8388608 + 196608);  // 4 MB

    k_wt<<<dim3(FOUT / 32, FIN / 32), dim3(32, 32), 0, stream>>>(W, WT);
    k_gemm<<<dim3(BATCH * NTOK / 64), 256, 0, stream>>>(x, WT, a, WhT, s1, s2);
    k_pack<<<dim3(1024), 256, 0, stream>>>(adj, mask64);
    k_attn<<<dim3(BATCH * NTOK / 64), 512, 0, stream>>>((const unsigned*)mask64, WhT,
                                                        s1, s2, out);
}

// Round 18
// 82.847 us; speedup vs baseline: 1.1007x; 1.1007x over previous
//
#include <hip/hip_runtime.h>
#include <hip/hip_fp16.h>

typedef _Float16 f16;
typedef _Float16 half4 __attribute__((ext_vector_type(4)));
typedef _Float16 half8 __attribute__((ext_vector_type(8)));
typedef float f32x4 __attribute__((ext_vector_type(4)));

#define BATCH 8
#define NTOK 2048
#define FIN 256
#define FOUT 256
#define ALPHA 0.2f

// WhT swizzled layout: [b][slab(32)][o(256)][u(8)][q(8)] f16; logical
// Wh[n][o] (n = slab*64 + jg8*8 + jq) lives at u = jg8 ^ (o & 7).
// Each slab is a contiguous 32 KB block == its LDS image in k_attn.

__device__ __forceinline__ void gload16(const void* g, void* l) {
    __builtin_amdgcn_global_load_lds(
        (const __attribute__((address_space(1))) unsigned int*)(g),
        (__attribute__((address_space(3))) unsigned int*)(l), 16, 0, 0);
}

// ---------------- K0: W[k][o] fp32 -> WT[o][k] fp16 ----------------
__global__ void k_wt(const float* __restrict__ W, f16* __restrict__ WT) {
    __shared__ float t[32][33];
    int o0 = blockIdx.x * 32, k0 = blockIdx.y * 32;
    int tx = threadIdx.x, ty = threadIdx.y;
    t[ty][tx] = W[(k0 + ty) * FOUT + o0 + tx];
    __syncthreads();
    WT[(o0 + ty) * FIN + (k0 + tx)] = (f16)t[tx][ty];
}

// ---------------- K1: gemm -> swizzled WhT slab + fused s1/s2 epilogue ----------------
__global__ __launch_bounds__(256) void k_gemm(const float* __restrict__ x,
                                              const f16* __restrict__ WT,
                                              const float* __restrict__ a,
                                              f16* __restrict__ WhT,
                                              float* __restrict__ s1,
                                              float* __restrict__ s2) {
    __shared__ __align__(16) char gsmem[46080];
    int t = threadIdx.x;
    int lane = t & 63, w = t >> 6;
    f16* Ah = (f16*)gsmem;               // [64][72]
    f16* Bt = (f16*)(gsmem + 9216);      // [256][72]
    int m0 = blockIdx.x * 64;
    int lr = lane & 15, lg = lane >> 4;
    f32x4 acc[4][4] = {};

    for (int k0 = 0; k0 < FIN; k0 += 64) {
        {
            int r = t >> 2, c = (t & 3) * 16;
            const float* src = x + (size_t)(m0 + r) * FIN + k0 + c;
            f32x4 v0 = *(const f32x4*)(src);
            f32x4 v1 = *(const f32x4*)(src + 4);
            f32x4 v2 = *(const f32x4*)(src + 8);
            f32x4 v3 = *(const f32x4*)(src + 12);
            half8 h0, h1;
#pragma unroll
            for (int q = 0; q < 4; q++) {
                h0[q] = (f16)v0[q]; h0[q + 4] = (f16)v1[q];
                h1[q] = (f16)v2[q]; h1[q + 4] = (f16)v3[q];
            }
            f16* dst = Ah + r * 72 + c;
            *(half8*)dst = h0;
            *(half8*)(dst + 8) = h1;
        }
        {
            const f16* src = WT + (size_t)t * FIN + k0;
            f16* dst = Bt + t * 72;
#pragma unroll
            for (int q = 0; q < 8; q++)
                *(half8*)(dst + q * 8) = *(const half8*)(src + q * 8);
        }
        __syncthreads();
#pragma unroll
        for (int kc = 0; kc < 2; kc++) {
            int krow = kc * 32 + lg * 8;
            half8 af[4], bf[4];
#pragma unroll
            for (int fi = 0; fi < 4; fi++)
                af[fi] = *(half8*)(Ah + (fi * 16 + lr) * 72 + krow);
#pragma unroll
            for (int fo = 0; fo < 4; fo++)
                bf[fo] = *(half8*)(Bt + (w * 64 + fo * 16 + lr) * 72 + krow);
#pragma unroll
            for (int fi = 0; fi < 4; fi++)
#pragma unroll
                for (int fo = 0; fo < 4; fo++)
                    acc[fi][fo] = __builtin_amdgcn_mfma_f32_16x16x32_f16(
                        af[fi], bf[fo], acc[fi][fo], 0, 0, 0);
        }
        __syncthreads();
    }

    int b = m0 >> 11;
    int slab_i = (m0 & (NTOK - 1)) >> 6;
    int nbase = m0 & (NTOK - 1);

    float* sred = (float*)gsmem;          // aliases Ah
    f16* slab = (f16*)(gsmem + 9216);     // 32 KB slab image (aliases Bt)
    float a1v[4], a2v[4];
#pragma unroll
    for (int fo = 0; fo < 4; fo++) {
        int o = w * 64 + fo * 16 + lr;
        a1v[fo] = a[o];
        a2v[fo] = a[FOUT + o];
    }
#pragma unroll
    for (int fi = 0; fi < 4; fi++) {
        f32x4 p1 = {}, p2 = {};
#pragma unroll
        for (int fo = 0; fo < 4; fo++) {
            p1 += acc[fi][fo] * a1v[fo];
            p2 += acc[fi][fo] * a2v[fo];
        }
#pragma unroll
        for (int q = 0; q < 4; q++) {
#pragma unroll
            for (int d = 1; d < 16; d <<= 1) {
                p1[q] += __shfl_xor(p1[q], d);
                p2[q] += __shfl_xor(p2[q], d);
            }
        }
        if (lr == 0) {
            int row = fi * 16 + lg * 4;
#pragma unroll
            for (int q = 0; q < 4; q++) {
                sred[w * 64 + row + q] = p1[q];
                sred[256 + w * 64 + row + q] = p2[q];
            }
        }
    }
#pragma unroll
    for (int fi = 0; fi < 4; fi++) {
        int jg8 = fi * 2 + (lg >> 1), jq0 = (lg & 1) * 4;
#pragma unroll
        for (int fo = 0; fo < 4; fo++) {
            int o = w * 64 + fo * 16 + lr;
            half4 hv;
#pragma unroll
            for (int q = 0; q < 4; q++) hv[q] = (f16)acc[fi][fo][q];
            *(half4*)(slab + o * 64 + ((jg8 ^ (o & 7)) * 8) + jq0) = hv;
        }
    }
    __syncthreads();

    if (t < 64) {
        s1[(size_t)b * NTOK + nbase + t] =
            sred[t] + sred[64 + t] + sred[128 + t] + sred[192 + t];
    } else if (t < 128) {
        int r2 = t - 64;
        s2[(size_t)b * NTOK + nbase + r2] =
            sred[256 + r2] + sred[320 + r2] + sred[384 + r2] + sred[448 + r2];
    }
    {
        const int4* sl = (const int4*)slab;
        int4* gd = (int4*)(WhT + ((size_t)(b * 32 + slab_i) * 256) * 64);
#pragma unroll
        for (int i = 0; i < 8; i++) gd[i * 256 + t] = sl[i * 256 + t];
    }
}

// ---------------- K3: self-packing fused attn ----------------
// Prologue: each wave reads its 8 rows' adj ROW-CONTIGUOUSLY (8 KB/row,
// lane = 32 consecutive ints, next row preloaded) and writes the 16 KB LDS
// bitmask. No pack kernel, no mask HBM round-trip, adj read once coalesced.
// Main loop: R12/R17-validated mask loop, mask now read from LDS.
// rowmax fold (s2max upper bound -> fixed softmax shift) kept from R17.
__global__ __launch_bounds__(512, 1) void k_attn(const int* __restrict__ adj,
                                                 const f16* __restrict__ WhT,
                                                 const float* __restrict__ s1g,
                                                 const float* __restrict__ s2g,
                                                 float* __restrict__ out) {
    __shared__ __align__(16) char smem[91264];
    f16* Bl = (f16*)smem;                               // 2 x 32 KB WhT slabs
    float* s2_lds = (float*)(smem + 65536);             // [2048]
    unsigned* mask_lds = (unsigned*)(smem + 73728);     // [64][66] u32, padded
    float* lpart = (float*)(smem + 90624);              // [2][64]
    float* wmax = (float*)(smem + 91136);               // [8]

    int b = blockIdx.x & 7;                             // batch -> XCD pinning
    int i0 = (blockIdx.x >> 3) * 64;
    int t = threadIdx.x;
    int lane = t & 63, w = t >> 6;
    int js = w & 1, oh = (w >> 1) & 1, rg = w >> 2;
    int lr = lane & 15, lg = lane >> 4;

    {   // s2 -> LDS + block max (rowmax fold)
        f32x4 sv4 = ((const f32x4*)(s2g + (size_t)b * NTOK))[t];
        ((f32x4*)s2_lds)[t] = sv4;
        float tmx = fmaxf(fmaxf(sv4[0], sv4[1]), fmaxf(sv4[2], sv4[3]));
#pragma unroll
        for (int d = 1; d < 64; d <<= 1) tmx = fmaxf(tmx, __shfl_xor(tmx, d));
        if (lane == 0) wmax[w] = tmx;
    }

    const char* wsrc = (const char*)WhT + (size_t)b * (32 * 32768);
    {   // slab 0 DMA
        const char* src = wsrc + (w * 4) * 1024 + lane * 16;
        char* dst = (char*)Bl + (w * 4) * 1024;
#pragma unroll
        for (int k = 0; k < 4; k++) gload16(src + k * 1024, dst + k * 1024);
    }

    {   // adj self-pack: wave w -> rows w*8 .. w*8+7, row-contiguous reads
        const int4* abase = (const int4*)(adj + ((size_t)(b * NTOK + i0 + w * 8)) * NTOK)
                            + lane * 8;
        int4 cur[8], nxt[8];
#pragma unroll
        for (int k = 0; k < 8; k++) cur[k] = abase[k];
        for (int r = 0; r < 8; r++) {
            if (r < 7) {
#pragma unroll
                for (int k = 0; k < 8; k++) nxt[k] = abase[(r + 1) * 512 + k];
            }
            unsigned m = 0;
#pragma unroll
            for (int k = 0; k < 8; k++) {
                m |= (unsigned)(cur[k].x > 0) << (k * 4);
                m |= (unsigned)(cur[k].y > 0) << (k * 4 + 1);
                m |= (unsigned)(cur[k].z > 0) << (k * 4 + 2);
                m |= (unsigned)(cur[k].w > 0) << (k * 4 + 3);
            }
            mask_lds[(w * 8 + r) * 66 + lane] = m;
#pragma unroll
            for (int k = 0; k < 8; k++) cur[k] = nxt[k];
        }
    }

    int rr0 = rg * 32 + lr;                             // row-in-block (fi=0)
    int r0 = i0 + rr0, r1 = r0 + 16;
    float s1r0 = s1g[(size_t)b * NTOK + r0];
    float s1r1 = s1g[(size_t)b * NTOK + r1];

    f32x4 acc0[8] = {}, acc1[8] = {};
    float l0 = 0.f, l1 = 0.f;
    int rswz = ((js * 4 + lg) ^ (lr & 7)) * 8;

    __syncthreads();                                    // s2+wmax+slab0+mask ready

    float s2m = wmax[0];
#pragma unroll
    for (int k = 1; k < 8; k++) s2m = fmaxf(s2m, wmax[k]);
    float tx0 = s1r0 + s2m;
    float mx0 = fmaxf(tx0, ALPHA * tx0);
    float tx1 = s1r1 + s2m;
    float mx1 = fmaxf(tx1, ALPHA * tx1);

    for (int s = 0; s < 32; s++) {
        int buf = s & 1;
        if (s < 31) {
            const char* src = wsrc + (size_t)(s + 1) * 32768 + (w * 4) * 1024 + lane * 16;
            char* dst = (char*)Bl + (buf ^ 1) * 32768 + (w * 4) * 1024;
#pragma unroll
            for (int k = 0; k < 4; k++) gload16(src + k * 1024, dst + k * 1024);
        }

        unsigned cw0 = mask_lds[rr0 * 66 + s * 2 + js];
        unsigned cw1 = mask_lds[(rr0 + 16) * 66 + s * 2 + js];
        unsigned bits0 = (cw0 >> (lg * 8)) & 0xffu;
        unsigned bits1 = (cw1 >> (lg * 8)) & 0xffu;

        int sb = s * 64 + js * 32 + lg * 8;
        f32x4 sA = *(const f32x4*)&s2_lds[sb];
        f32x4 sB = *(const f32x4*)&s2_lds[sb + 4];

        half8 ph0, ph1;
#pragma unroll
        for (int q = 0; q < 8; q++) {
            float sv = q < 4 ? sA[q & 3] : sB[q & 3];
            float sx = s1r0 + sv;
            float ev = fmaxf(sx, ALPHA * sx);
            float p = ((bits0 >> q) & 1) ? __expf(ev - mx0) : 0.f;
            l0 += p; ph0[q] = (f16)p;
            float sy = s1r1 + sv;
            float eu = fmaxf(sy, ALPHA * sy);
            float u = ((bits1 >> q) & 1) ? __expf(eu - mx1) : 0.f;
            l1 += u; ph1[q] = (f16)u;
        }

        const f16* bbase = Bl + buf * 16384 + (oh * 128 + lr) * 64 + rswz;
#pragma unroll
        for (int ot = 0; ot < 8; ot++) {
            half8 bf = *(const half8*)(bbase + ot * (16 * 64));
            acc0[ot] = __builtin_amdgcn_mfma_f32_16x16x32_f16(ph0, bf, acc0[ot], 0, 0, 0);
            acc1[ot] = __builtin_amdgcn_mfma_f32_16x16x32_f16(ph1, bf, acc1[ot], 0, 0, 0);
        }
        __syncthreads();
    }

    l0 += __shfl_xor(l0, 16); l0 += __shfl_xor(l0, 32);
    l1 += __shfl_xor(l1, 16); l1 += __shfl_xor(l1, 32);
    if (oh == 0 && lg == 0) {
        lpart[js * 64 + rg * 32 + lr] = l0;
        lpart[js * 64 + rg * 32 + 16 + lr] = l1;
    }
    __syncthreads();

    float* accx = (float*)smem;                         // [64][260], aliases Bl+s2
    if (js == 1) {
#pragma unroll
        for (int ot = 0; ot < 8; ot++)
#pragma unroll
            for (int q = 0; q < 4; q++) {
                accx[(rg * 32 + lg * 4 + q) * 260 + oh * 128 + ot * 16 + lr] = acc0[ot][q];
                accx[(rg * 32 + 16 + lg * 4 + q) * 260 + oh * 128 + ot * 16 + lr] = acc1[ot][q];
            }
    }
    __syncthreads();
    if (js == 0) {
        f32x4 rl0, rl1;
#pragma unroll
        for (int q = 0; q < 4; q++) {
            int ra = rg * 32 + lg * 4 + q, rb = ra + 16;
            rl0[q] = 1.f / (lpart[ra] + lpart[64 + ra]);
            rl1[q] = 1.f / (lpart[rb] + lpart[64 + rb]);
        }
#pragma unroll
        for (int ot = 0; ot < 8; ot++) {
            int o = oh * 128 + ot * 16 + lr;
#pragma unroll
            for (int q = 0; q < 4; q++) {
                int ra = rg * 32 + lg * 4 + q;
                float u = (acc0[ot][q] + accx[ra * 260 + o]) * rl0[q];
                u = u > 0.f ? u : __expf(u) - 1.f;
                __builtin_nontemporal_store(u, &out[((size_t)(b * NTOK + i0 + ra)) * FOUT + o]);
                int rb = ra + 16;
                float v = (acc1[ot][q] + accx[rb * 260 + o]) * rl1[q];
                v = v > 0.f ? v : __expf(v) - 1.f;
                __builtin_nontemporal_store(v, &out[((size_t)(b * NTOK + i0 + rb)) * FOUT + o]);
            }
        }
    }
}

extern "C" void kernel_launch(void* const* d_in, const int* in_sizes, int n_in,
                              void* d_out, int out_size, void* d_ws, size_t ws_size,
                              hipStream_t stream) {
    const float* x = (const float*)d_in[0];
    const int* adj = (const int*)d_in[1];
    const float* W = (const float*)d_in[2];
    const float* a = (const float*)d_in[3];
    float* out = (float*)d_out;

    char* ws = (char*)d_ws;
    f16* WT = (f16*)ws;                                     // 128 KB
    f16* WhT = (f16*)(ws + 131072);                         // 8 MB swizzled
    float* s1 = (float*)(ws + 131072 + 8388608);            // 64 KB
    float* s2 = s1 + BATCH * NTOK;                          // 64 KB

    k_wt<<<dim3(FOUT / 32, FIN / 32), dim3(32, 32), 0, stream>>>(W, WT);
    k_gemm<<<dim3(BATCH * NTOK / 64), 256, 0, stream>>>(x, WT, a, WhT, s1, s2);
    k_attn<<<dim3(BATCH * NTOK / 64), 512, 0, stream>>>(adj, WhT, s1, s2, out);
}